// Round 4
// baseline (311.508 us; speedup 1.0000x reference)
//
#include <hip/hip_runtime.h>
#include <hip/hip_bf16.h>

constexpr int Bt    = 131072;
constexpr int OBS   = 194;

// ---- d_ws layout ----
// bytes [0, 57344)        : W1B | WC1B   (layer-1 B-frags, bf16)
// bytes [57344, 92160)    : W2B | WC2B | WHB (layer-2 + head B-frags)
// bytes [98304, 229376)   : evG (1 byte per row)
// bytes [262144, +32 MiB) : hG  (layer-1 output, packed-C layout [tile][2][16][64] bf16)
constexpr int W1B_S  = 0;
constexpr int WC1B_S = 14336;
constexpr int W2B_S  = 28672;
constexpr int WC2B_S = 36864;
constexpr int WHB_S  = 45056;
constexpr size_t EVG_B = 98304;     // byte offset of evG
constexpr size_t HG_S  = 131072;    // short offset of hG (byte 262144)

typedef short bf8   __attribute__((ext_vector_type(8)));
typedef float f32x4 __attribute__((ext_vector_type(4)));
typedef unsigned int u32;

__device__ __forceinline__ short f2bs(float f) {
    union { __hip_bfloat16 h; short s; } u;
    u.h = __float2bfloat16(f);
    return u.s;
}
__device__ __forceinline__ float bs2f(short s) {
    union { short s; __hip_bfloat16 h; } u;
    u.s = s;
    return __bfloat162float(u.h);
}
__device__ __forceinline__ u32 pk2(float a, float b) {
    union { __hip_bfloat162 h; u32 u; } r;
    r.h = __float22bfloat162_rn(float2{a, b});
    return r.u;
}
__device__ __forceinline__ float fast_tanh(float v) {
    v = fminf(fmaxf(v, -15.f), 15.f);
    float e = __expf(2.f * v);
    return (e - 1.f) * __builtin_amdgcn_rcpf(e + 1.f);
}
// g: per-lane global address. s: WAVE-UNIFORM LDS base — HW writes lane i at s + i*16.
__device__ __forceinline__ void dma16(const void* g, void* s) {
    __builtin_amdgcn_global_load_lds(
        (const __attribute__((address_space(1))) u32*)g,
        (__attribute__((address_space(3))) u32*)s, 16, 0, 0);
}

// ---------------- prep: weights -> B-fragment layout in d_ws (unchanged) ----------------
__global__ void __launch_bounds__(256) prep(
    const float* __restrict__ W1, const float* __restrict__ b1,
    const float* __restrict__ W2, const float* __restrict__ Wh,
    const float* __restrict__ Wc1, const float* __restrict__ bc1,
    const float* __restrict__ Wc2, const float* __restrict__ Wc3,
    short* __restrict__ ws)
{
    const int gid = blockIdx.x * 256 + threadIdx.x;
    const int gsz = gridDim.x * 256;

    for (int i = gid; i < 14336; i += gsz) {
        int j = i & 7, l = (i >> 3) & 63, nt = (i >> 9) & 3, kb = i >> 11;
        int k = kb * 32 + ((l >> 4) << 3) + j;
        int n = nt * 16 + (l & 15);
        short v1 = 0, v2 = 0;
        if (k < OBS) {
            v1 = f2bs(W1[k * 64 + n]);
            v2 = f2bs(Wc1[k * 64 + n]);
        } else if (k == OBS) {              // bias row (A supplies 1.0)
            v1 = f2bs(b1[n]);
            v2 = f2bs(bc1[n]);
        }
        ws[W1B_S + i]  = v1;
        ws[WC1B_S + i] = v2;
    }
    for (int i = gid; i < 8192; i += gsz) {
        int j = i & 7, l = (i >> 3) & 63, nt = (i >> 9) & 3, kb = i >> 11;
        int s = kb * 32 + ((l >> 4) << 3) + j;
        int kp = (s & 3) * 16 + (s >> 2);   // gamma(s)
        int n = nt * 16 + (l & 15);
        ws[W2B_S + i]  = f2bs(W2[kp * 64 + n]);
        ws[WC2B_S + i] = f2bs(Wc2[kp * 64 + n]);
    }
    for (int i = gid; i < 1024; i += gsz) {
        int j = i & 7, l = (i >> 3) & 63, kb = i >> 9;
        int s = kb * 32 + ((l >> 4) << 3) + j;
        int kp = (s & 3) * 16 + (s >> 2);
        int cc = l & 15;
        float v;
        if (cc == 15) v = Wc3[kp];
        else { int e = cc / 5, a = cc - 5 * e; v = Wh[(e * 64 + kp) * 5 + a]; }
        ws[WHB_S + i] = f2bs(v);
    }
}

// ---------------- trunk1: layer 1 (actor+critic) + ev, direct reg loads ----------------
// LDS = weights only (56 KB) -> 2 blocks/CU, 16 waves/CU (4/SIMD).
// Each wave: 2 tiles of 16 rows, x loaded per-lane (float2, 776-B row stride; L1
// serves the 128-B row segments across the 4 consecutive j-loads).
__global__ void __launch_bounds__(512, 4) trunk1(
    const float* __restrict__ x, const short* __restrict__ ws,
    short* __restrict__ hG, unsigned char* __restrict__ evG)
{
    __shared__ __align__(16) char smem[57344];
    const int t = threadIdx.x;
    const int l = t & 63, q = (t >> 4) & 3, c = t & 15;
    const int wu = __builtin_amdgcn_readfirstlane(t >> 6);   // wave id, SGPR

    // weights -> LDS: 56 x 1024-B chunks, 7 per wave, uniform dest
    #pragma unroll
    for (int i = 0; i < 7; ++i) {
        int ch = wu * 7 + i;
        dma16((const char*)ws + ch * 1024 + l * 16, smem + ch * 1024);
    }

    const bf8* fW1L  = reinterpret_cast<const bf8*>(smem);
    const bf8* fWc1L = reinterpret_cast<const bf8*>(smem + 28672);

    const int t0 = blockIdx.x * 16 + wu * 2;   // 512 blocks x 8 waves x 2 tiles = 8192

    float2 raw[24]; float2 rt6;
    auto loadraw = [&](int tt) {
        const float* xr = x + (size_t)tt * 16 * OBS + (size_t)c * OBS;
        #pragma unroll
        for (int kb = 0; kb < 6; ++kb) {
            const float2* p = reinterpret_cast<const float2*>(xr + kb * 32 + q * 8);
            raw[kb * 4 + 0] = p[0]; raw[kb * 4 + 1] = p[1];
            raw[kb * 4 + 2] = p[2]; raw[kb * 4 + 3] = p[3];
        }
        rt6 = float2{0.f, 0.f};
        if (q == 0) rt6 = *reinterpret_cast<const float2*>(xr + 192);
    };

    union AF { u32 u[4]; bf8 v; } af[7];
    auto packaf = [&](int tt) {
        #pragma unroll
        for (int kb = 0; kb < 6; ++kb) {
            af[kb].u[0] = pk2(raw[kb * 4 + 0].x, raw[kb * 4 + 0].y);
            af[kb].u[1] = pk2(raw[kb * 4 + 1].x, raw[kb * 4 + 1].y);
            af[kb].u[2] = pk2(raw[kb * 4 + 2].x, raw[kb * 4 + 2].y);
            af[kb].u[3] = pk2(raw[kb * 4 + 3].x, raw[kb * 4 + 3].y);
        }
        af[6].u[0] = 0; af[6].u[1] = 0; af[6].u[2] = 0; af[6].u[3] = 0;
        if (q == 0) {                       // k=192,193 data; k=194 -> 1.0 (bias row)
            af[6].u[0] = pk2(rt6.x, rt6.y);
            af[6].u[1] = pk2(1.0f, 0.0f);
        }
        if (l < 16) {                       // ev = argmax(x[0..2]) (q==0 lanes, l==c)
            int ev = 0; float b = raw[0].x;
            if (raw[0].y > b) { b = raw[0].y; ev = 1; }
            if (raw[1].x > b) ev = 2;
            evG[tt * 16 + l] = (unsigned char)ev;
        }
    };

    loadraw(t0);
    __syncthreads();   // weights (and tile-A loads) resident

    #pragma unroll 1
    for (int i = 0; i < 2; ++i) {
        const int tt = t0 + i;
        packaf(tt);

        // ---- layer 1: actor + critic (bias folded via k=194 row) ----
        f32x4 aa[4], ac[4];
        #pragma unroll
        for (int nt = 0; nt < 4; ++nt) {
            aa[nt] = f32x4{0.f, 0.f, 0.f, 0.f};
            ac[nt] = f32x4{0.f, 0.f, 0.f, 0.f};
        }
        #pragma unroll
        for (int kb = 0; kb < 7; ++kb) {
            bf8 a = af[kb].v;
            #pragma unroll
            for (int nt = 0; nt < 4; ++nt) {
                aa[nt] = __builtin_amdgcn_mfma_f32_16x16x32_bf16(a, fW1L [(kb * 4 + nt) * 64 + l], aa[nt], 0, 0, 0);
                ac[nt] = __builtin_amdgcn_mfma_f32_16x16x32_bf16(a, fWc1L[(kb * 4 + nt) * 64 + l], ac[nt], 0, 0, 0);
            }
        }

        // ---- issue next tile's loads (latency hidden under tanh/stores + TLP) ----
        if (i == 0) loadraw(t0 + 1);

        // ---- tanh -> packed-C layout straight to global (no LDS bounce) ----
        short* hGt = hG + (size_t)tt * 2048;
        #pragma unroll
        for (int r = 0; r < 4; ++r) {
            uint2 pa, pc;
            pa.x = pk2(fast_tanh(aa[0][r]), fast_tanh(aa[1][r]));
            pa.y = pk2(fast_tanh(aa[2][r]), fast_tanh(aa[3][r]));
            pc.x = pk2(fast_tanh(ac[0][r]), fast_tanh(ac[1][r]));
            pc.y = pk2(fast_tanh(ac[2][r]), fast_tanh(ac[3][r]));
            *reinterpret_cast<uint2*>(hGt + (q * 4 + r) * 64 + 4 * c)        = pa;
            *reinterpret_cast<uint2*>(hGt + 1024 + (q * 4 + r) * 64 + 4 * c) = pc;
        }
    }
}

// ---------------- head2: layer 2 + head + epilogue (2 blocks/CU) ----------------
constexpr int F2_W   = 34816;            // W2B|WC2B|WHB in LDS
constexpr int F2_PW  = 5248;             // per-wave: ha 2304 | hc 2304 | lw 576 | vb 64
constexpr int F2_LDS = F2_W + 8 * F2_PW; // 76800 B -> 2 blocks/CU

__global__ void __launch_bounds__(512, 4) head2(
    const int* __restrict__ act_in,
    const float* __restrict__ b2, const float* __restrict__ bc2,
    const float* __restrict__ bh, const float* __restrict__ bc3,
    const short* __restrict__ ws,
    const short* __restrict__ hG, const unsigned char* __restrict__ evG,
    float* __restrict__ out)
{
    __shared__ __align__(16) char smem[F2_LDS];
    const int t = threadIdx.x;
    const int l = t & 63, q = (t >> 4) & 3, c = t & 15;
    const int wu = __builtin_amdgcn_readfirstlane(t >> 6);   // wave id, SGPR

    // weights -> LDS: 34816 B = 34 x 1024-B chunks, uniform dest (wave-level guard)
    #pragma unroll
    for (int i = 0; i < 5; ++i) {
        int ch = wu + i * 8;
        if (ch < 34)
            dma16((const char*)ws + 57344 + ch * 1024 + l * 16, smem + ch * 1024);
    }

    float b2v[4], bc2v[4];
    #pragma unroll
    for (int nt = 0; nt < 4; ++nt) {
        b2v[nt]  = b2[nt * 16 + c];
        bc2v[nt] = bc2[nt * 16 + c];
    }
    float bhv = (c < 15) ? bh[c] : bc3[0];

    __syncthreads();

    const bf8* fW2L  = reinterpret_cast<const bf8*>(smem);
    const bf8* fWc2L = reinterpret_cast<const bf8*>(smem + 16384);
    const bf8* fWhL  = reinterpret_cast<const bf8*>(smem + 32768);
    short* ha = reinterpret_cast<short*>(smem + F2_W + wu * F2_PW);
    short* hc = ha + 1152;
    short* lw = reinterpret_cast<short*>(smem + F2_W + wu * F2_PW + 4608);
    float* vb = reinterpret_cast<float*>(smem + F2_W + wu * F2_PW + 5184);

    #pragma unroll 1
    for (int i = 0; i < 2; ++i) {
        const int tt = blockIdx.x * 16 + wu * 2 + i;
        const int gm = tt * 16 + c;
        int act = 0, evc = 0;
        if (l < 16) { act = act_in[gm]; evc = evG[gm]; }

        // ---- load packed-C h tile (coalesced uint2) and bounce through LDS ----
        const short* hGt = hG + (size_t)tt * 2048;
        uint2 va[4], vc2[4];
        #pragma unroll
        for (int r = 0; r < 4; ++r) {
            va[r]  = *reinterpret_cast<const uint2*>(hGt + (q * 4 + r) * 64 + 4 * c);
            vc2[r] = *reinterpret_cast<const uint2*>(hGt + 1024 + (q * 4 + r) * 64 + 4 * c);
        }
        #pragma unroll
        for (int r = 0; r < 4; ++r) {
            *reinterpret_cast<uint2*>(&ha[(q * 4 + r) * 72 + 4 * c]) = va[r];
            *reinterpret_cast<uint2*>(&hc[(q * 4 + r) * 72 + 4 * c]) = vc2[r];
        }
        // layer-2 A-frags (wave-local transpose read)
        bf8 xa[2], xc[2];
        #pragma unroll
        for (int kb = 0; kb < 2; ++kb) {
            xa[kb] = *reinterpret_cast<const bf8*>(&ha[c * 72 + kb * 32 + q * 8]);
            xc[kb] = *reinterpret_cast<const bf8*>(&hc[c * 72 + kb * 32 + q * 8]);
        }

        // ---- layer 2 (bias via acc init) ----
        f32x4 aa[4], ac[4];
        #pragma unroll
        for (int nt = 0; nt < 4; ++nt) {
            aa[nt] = f32x4{b2v[nt], b2v[nt], b2v[nt], b2v[nt]};
            ac[nt] = f32x4{bc2v[nt], bc2v[nt], bc2v[nt], bc2v[nt]};
        }
        #pragma unroll
        for (int kb = 0; kb < 2; ++kb) {
            #pragma unroll
            for (int nt = 0; nt < 4; ++nt) {
                aa[nt] = __builtin_amdgcn_mfma_f32_16x16x32_bf16(xa[kb], fW2L [(kb * 4 + nt) * 64 + l], aa[nt], 0, 0, 0);
                ac[nt] = __builtin_amdgcn_mfma_f32_16x16x32_bf16(xc[kb], fWc2L[(kb * 4 + nt) * 64 + l], ac[nt], 0, 0, 0);
            }
        }
        #pragma unroll
        for (int r = 0; r < 4; ++r) {
            uint2 pa, pc;
            pa.x = pk2(fast_tanh(aa[0][r]), fast_tanh(aa[1][r]));
            pa.y = pk2(fast_tanh(aa[2][r]), fast_tanh(aa[3][r]));
            pc.x = pk2(fast_tanh(ac[0][r]), fast_tanh(ac[1][r]));
            pc.y = pk2(fast_tanh(ac[2][r]), fast_tanh(ac[3][r]));
            *reinterpret_cast<uint2*>(&ha[(q * 4 + r) * 72 + 4 * c]) = pa;
            *reinterpret_cast<uint2*>(&hc[(q * 4 + r) * 72 + 4 * c]) = pc;
        }

        // ---- head: feat[16x64] @ [64x16] (cols 0-14 logits, col 15 value) ----
        {
            f32x4 lg = f32x4{bhv, bhv, bhv, bhv};
            f32x4 vv = f32x4{bhv, bhv, bhv, bhv};
            #pragma unroll
            for (int kb = 0; kb < 2; ++kb) {
                bf8 bw = fWhL[kb * 64 + l];
                bf8 fa = *reinterpret_cast<const bf8*>(&ha[c * 72 + kb * 32 + q * 8]);
                bf8 fc = *reinterpret_cast<const bf8*>(&hc[c * 72 + kb * 32 + q * 8]);
                lg = __builtin_amdgcn_mfma_f32_16x16x32_bf16(fa, bw, lg, 0, 0, 0);
                vv = __builtin_amdgcn_mfma_f32_16x16x32_bf16(fc, bw, vv, 0, 0, 0);
            }
            #pragma unroll
            for (int r = 0; r < 4; ++r)
                lw[(q * 4 + r) * 18 + c] = f2bs(lg[r]);
            if (c == 15) {
                #pragma unroll
                for (int r = 0; r < 4; ++r)
                    vb[q * 4 + r] = vv[r];
            }
        }

        // ---- epilogue: lanes 0-15 (wave-local LDS, in-order DS pipe) ----
        if (l < 16) {
            float lg[5];
            #pragma unroll
            for (int a = 0; a < 5; ++a)
                lg[a] = bs2f(lw[c * 18 + evc * 5 + a]);
            float mx = lg[0];
            #pragma unroll
            for (int a = 1; a < 5; ++a) mx = fmaxf(mx, lg[a]);
            float se = 0.f;
            #pragma unroll
            for (int a = 0; a < 5; ++a) se += __expf(lg[a] - mx);
            float lse = __logf(se) + mx;
            float lsel = lg[0];
            #pragma unroll
            for (int a = 1; a < 5; ++a) lsel = (act == a) ? lg[a] : lsel;
            float ent = 0.f;
            #pragma unroll
            for (int a = 0; a < 5; ++a) { float lp = lg[a] - lse; ent -= __expf(lp) * lp; }

            out[gm]          = (float)act;
            out[Bt + gm]     = lsel - lse;
            out[2 * Bt + gm] = ent;
            out[3 * Bt + gm] = vb[c];
        }
    }
}

extern "C" void kernel_launch(void* const* d_in, const int* in_sizes, int n_in,
                              void* d_out, int out_size, void* d_ws, size_t ws_size,
                              hipStream_t stream) {
    const float* x   = (const float*)d_in[0];
    const int*   act = (const int*)  d_in[1];
    const float* W1  = (const float*)d_in[2];
    const float* b1  = (const float*)d_in[3];
    const float* W2  = (const float*)d_in[4];
    const float* b2  = (const float*)d_in[5];
    const float* Wh  = (const float*)d_in[6];
    const float* bh  = (const float*)d_in[7];
    const float* Wc1 = (const float*)d_in[8];
    const float* bc1 = (const float*)d_in[9];
    const float* Wc2 = (const float*)d_in[10];
    const float* bc2 = (const float*)d_in[11];
    const float* Wc3 = (const float*)d_in[12];
    const float* bc3 = (const float*)d_in[13];
    float* out = (float*)d_out;
    short* ws  = (short*)d_ws;
    short* hG  = ws + HG_S;
    unsigned char* evG = (unsigned char*)d_ws + EVG_B;

    hipLaunchKernelGGL(prep, dim3(32), dim3(256), 0, stream,
                       W1, b1, W2, Wh, Wc1, bc1, Wc2, Wc3, ws);
    hipLaunchKernelGGL(trunk1, dim3(512), dim3(512), 0, stream,
                       x, ws, hG, evG);
    hipLaunchKernelGGL(head2, dim3(512), dim3(512), 0, stream,
                       act, b2, bc2, bh, bc3, ws, hG, evG, out);
}

// Round 5
// 197.072 us; speedup vs baseline: 1.5807x; 1.5807x over previous
//
#include <hip/hip_runtime.h>
#include <hip/hip_bf16.h>

constexpr int Bt    = 131072;
constexpr int OBS   = 194;

// ---- d_ws layout ----
// bytes [0, 57344)        : W1B | WC1B   (layer-1 B-frags, bf16)
// bytes [57344, 92160)    : W2B | WC2B | WHB (layer-2 + head B-frags)
// bytes [98304, 229376)   : evG (1 byte per row)
// bytes [262144, +32 MiB) : hG  (layer-1 output, packed-C layout, slot (r*4+q), bf16)
constexpr int W1B_S  = 0;
constexpr int WC1B_S = 14336;
constexpr int W2B_S  = 28672;
constexpr int WC2B_S = 36864;
constexpr int WHB_S  = 45056;
constexpr size_t EVG_B = 98304;     // byte offset of evG
constexpr size_t HG_S  = 131072;    // short offset of hG (byte 262144)

typedef short bf8   __attribute__((ext_vector_type(8)));
typedef float f32x4 __attribute__((ext_vector_type(4)));
typedef unsigned int u32;

__device__ __forceinline__ short f2bs(float f) {
    union { __hip_bfloat16 h; short s; } u;
    u.h = __float2bfloat16(f);
    return u.s;
}
__device__ __forceinline__ float bs2f(short s) {
    union { short s; __hip_bfloat16 h; } u;
    u.s = s;
    return __bfloat162float(u.h);
}
__device__ __forceinline__ u32 pk2(float a, float b) {
    union { __hip_bfloat162 h; u32 u; } r;
    r.h = __float22bfloat162_rn(float2{a, b});
    return r.u;
}
__device__ __forceinline__ float fast_tanh(float v) {
    v = fminf(fmaxf(v, -15.f), 15.f);
    float e = __expf(2.f * v);
    return (e - 1.f) * __builtin_amdgcn_rcpf(e + 1.f);
}
// g: per-lane global address. s: WAVE-UNIFORM LDS base — HW writes lane i at s + i*16.
__device__ __forceinline__ void dma16(const void* g, void* s) {
    __builtin_amdgcn_global_load_lds(
        (const __attribute__((address_space(1))) u32*)g,
        (__attribute__((address_space(3))) u32*)s, 16, 0, 0);
}

// ---------------- prep: weights -> B-fragment layout in d_ws (unchanged) ----------------
__global__ void __launch_bounds__(256) prep(
    const float* __restrict__ W1, const float* __restrict__ b1,
    const float* __restrict__ W2, const float* __restrict__ Wh,
    const float* __restrict__ Wc1, const float* __restrict__ bc1,
    const float* __restrict__ Wc2, const float* __restrict__ Wc3,
    short* __restrict__ ws)
{
    const int gid = blockIdx.x * 256 + threadIdx.x;
    const int gsz = gridDim.x * 256;

    for (int i = gid; i < 14336; i += gsz) {
        int j = i & 7, l = (i >> 3) & 63, nt = (i >> 9) & 3, kb = i >> 11;
        int k = kb * 32 + ((l >> 4) << 3) + j;
        int n = nt * 16 + (l & 15);
        short v1 = 0, v2 = 0;
        if (k < OBS) {
            v1 = f2bs(W1[k * 64 + n]);
            v2 = f2bs(Wc1[k * 64 + n]);
        } else if (k == OBS) {              // bias row (A supplies 1.0)
            v1 = f2bs(b1[n]);
            v2 = f2bs(bc1[n]);
        }
        ws[W1B_S + i]  = v1;
        ws[WC1B_S + i] = v2;
    }
    for (int i = gid; i < 8192; i += gsz) {
        int j = i & 7, l = (i >> 3) & 63, nt = (i >> 9) & 3, kb = i >> 11;
        int s = kb * 32 + ((l >> 4) << 3) + j;
        int kp = (s & 3) * 16 + (s >> 2);   // gamma(s)
        int n = nt * 16 + (l & 15);
        ws[W2B_S + i]  = f2bs(W2[kp * 64 + n]);
        ws[WC2B_S + i] = f2bs(Wc2[kp * 64 + n]);
    }
    for (int i = gid; i < 1024; i += gsz) {
        int j = i & 7, l = (i >> 3) & 63, kb = i >> 9;
        int s = kb * 32 + ((l >> 4) << 3) + j;
        int kp = (s & 3) * 16 + (s >> 2);
        int cc = l & 15;
        float v;
        if (cc == 15) v = Wc3[kp];
        else { int e = cc / 5, a = cc - 5 * e; v = Wh[(e * 64 + kp) * 5 + a]; }
        ws[WHB_S + i] = f2bs(v);
    }
}

// ---------------- trunk1: layer 1 (actor+critic) + ev ----------------
// Weights-only LDS (56 KB) -> 2 blocks/CU, 16 waves/CU. One 16-row tile per wave.
// x loaded per-lane as float4 and packed to bf16 IMMEDIATELY (no raw[] live range,
// no spills). Latency hidden by TLP (4+ waves/SIMD), not software pipelining.
__global__ void __launch_bounds__(512, 2) trunk1(
    const float* __restrict__ x, const short* __restrict__ ws,
    short* __restrict__ hG, unsigned char* __restrict__ evG)
{
    __shared__ __align__(16) char smem[57344];
    const int t = threadIdx.x;
    const int l = t & 63, q = (t >> 4) & 3, c = t & 15;
    const int wu = __builtin_amdgcn_readfirstlane(t >> 6);   // wave id, SGPR

    // weights -> LDS: 56 x 1024-B chunks, 7 per wave, uniform dest
    #pragma unroll
    for (int i = 0; i < 7; ++i) {
        int ch = wu * 7 + i;
        dma16((const char*)ws + ch * 1024 + l * 16, smem + ch * 1024);
    }

    const bf8* fW1L  = reinterpret_cast<const bf8*>(smem);
    const bf8* fWc1L = reinterpret_cast<const bf8*>(smem + 28672);

    const int tt = blockIdx.x * 8 + wu;              // 1024 blocks x 8 waves = 8192 tiles
    const float* xr = x + (size_t)tt * 16 * OBS + (size_t)c * OBS;

    // ---- load + pack in one step: lane (q,c) holds A[row=c][k = kb*32+q*8 .. +8) ----
    union AF { u32 u[4]; bf8 v; } af[7];
    float4 f40;                                      // row c floats 0-3 (valid for q==0)
    #pragma unroll
    for (int kb = 0; kb < 6; ++kb) {
        float4 a = *reinterpret_cast<const float4*>(xr + kb * 32 + q * 8);
        float4 b = *reinterpret_cast<const float4*>(xr + kb * 32 + q * 8 + 4);
        if (kb == 0) f40 = a;
        af[kb].u[0] = pk2(a.x, a.y);
        af[kb].u[1] = pk2(a.z, a.w);
        af[kb].u[2] = pk2(b.x, b.y);
        af[kb].u[3] = pk2(b.z, b.w);
    }
    af[6].u[0] = 0; af[6].u[1] = 0; af[6].u[2] = 0; af[6].u[3] = 0;
    if (q == 0) {                       // k=192,193 data; k=194 -> 1.0 (bias row)
        float2 v = *reinterpret_cast<const float2*>(xr + 192);
        af[6].u[0] = pk2(v.x, v.y);
        af[6].u[1] = pk2(1.0f, 0.0f);
    }
    // ---- ev = argmax(x[0..2]) for rows 0-15 (lanes l<16 have q==0, c==l) ----
    if (l < 16) {
        int ev = 0; float b = f40.x;
        if (f40.y > b) { b = f40.y; ev = 1; }
        if (f40.z > b) ev = 2;
        evG[tt * 16 + l] = (unsigned char)ev;
    }

    __syncthreads();   // weights resident

    // ---- layer 1: actor + critic (bias folded via k=194 row) ----
    f32x4 aa[4], ac[4];
    #pragma unroll
    for (int nt = 0; nt < 4; ++nt) {
        aa[nt] = f32x4{0.f, 0.f, 0.f, 0.f};
        ac[nt] = f32x4{0.f, 0.f, 0.f, 0.f};
    }
    #pragma unroll
    for (int kb = 0; kb < 7; ++kb) {
        bf8 a = af[kb].v;
        #pragma unroll
        for (int nt = 0; nt < 4; ++nt) {
            aa[nt] = __builtin_amdgcn_mfma_f32_16x16x32_bf16(a, fW1L [(kb * 4 + nt) * 64 + l], aa[nt], 0, 0, 0);
            ac[nt] = __builtin_amdgcn_mfma_f32_16x16x32_bf16(a, fWc1L[(kb * 4 + nt) * 64 + l], ac[nt], 0, 0, 0);
        }
    }

    // ---- tanh -> packed-C straight to global, slot (r*4+q): 512-B contiguous/instr ----
    // lane (q,c) reg r holds C[row=q*4+r][cols nt*16+c]; slot content = that row/colgroup.
    short* hGt = hG + (size_t)tt * 2048;
    #pragma unroll
    for (int r = 0; r < 4; ++r) {
        uint2 pa, pc;
        pa.x = pk2(fast_tanh(aa[0][r]), fast_tanh(aa[1][r]));
        pa.y = pk2(fast_tanh(aa[2][r]), fast_tanh(aa[3][r]));
        pc.x = pk2(fast_tanh(ac[0][r]), fast_tanh(ac[1][r]));
        pc.y = pk2(fast_tanh(ac[2][r]), fast_tanh(ac[3][r]));
        *reinterpret_cast<uint2*>(hGt + (r * 4 + q) * 64 + 4 * c)        = pa;
        *reinterpret_cast<uint2*>(hGt + 1024 + (r * 4 + q) * 64 + 4 * c) = pc;
    }
}

// ---------------- head2: layer 2 + head + epilogue (2 blocks/CU) ----------------
constexpr int F2_W   = 34816;            // W2B|WC2B|WHB in LDS
constexpr int F2_PW  = 5248;             // per-wave: ha 2304 | hc 2304 | lw 576 | vb 64
constexpr int F2_LDS = F2_W + 8 * F2_PW; // 76800 B -> 2 blocks/CU

__global__ void __launch_bounds__(512, 2) head2(
    const int* __restrict__ act_in,
    const float* __restrict__ b2, const float* __restrict__ bc2,
    const float* __restrict__ bh, const float* __restrict__ bc3,
    const short* __restrict__ ws,
    const short* __restrict__ hG, const unsigned char* __restrict__ evG,
    float* __restrict__ out)
{
    __shared__ __align__(16) char smem[F2_LDS];
    const int t = threadIdx.x;
    const int l = t & 63, q = (t >> 4) & 3, c = t & 15;
    const int wu = __builtin_amdgcn_readfirstlane(t >> 6);   // wave id, SGPR

    // weights -> LDS: 34816 B = 34 x 1024-B chunks, uniform dest (wave-level guard)
    #pragma unroll
    for (int i = 0; i < 5; ++i) {
        int ch = wu + i * 8;
        if (ch < 34)
            dma16((const char*)ws + 57344 + ch * 1024 + l * 16, smem + ch * 1024);
    }

    float b2v[4], bc2v[4];
    #pragma unroll
    for (int nt = 0; nt < 4; ++nt) {
        b2v[nt]  = b2[nt * 16 + c];
        bc2v[nt] = bc2[nt * 16 + c];
    }
    float bhv = (c < 15) ? bh[c] : bc3[0];

    __syncthreads();

    const bf8* fW2L  = reinterpret_cast<const bf8*>(smem);
    const bf8* fWc2L = reinterpret_cast<const bf8*>(smem + 16384);
    const bf8* fWhL  = reinterpret_cast<const bf8*>(smem + 32768);
    short* ha = reinterpret_cast<short*>(smem + F2_W + wu * F2_PW);
    short* hc = ha + 1152;
    short* lw = reinterpret_cast<short*>(smem + F2_W + wu * F2_PW + 4608);
    float* vb = reinterpret_cast<float*>(smem + F2_W + wu * F2_PW + 5184);

    #pragma unroll 1
    for (int i = 0; i < 2; ++i) {
        const int tt = blockIdx.x * 16 + wu * 2 + i;
        const int gm = tt * 16 + c;
        int act = 0, evc = 0;
        if (l < 16) { act = act_in[gm]; evc = evG[gm]; }

        // ---- load packed-C h tile (slot (r*4+q): 512-B contiguous/instr) ----
        const short* hGt = hG + (size_t)tt * 2048;
        uint2 va[4], vc2[4];
        #pragma unroll
        for (int r = 0; r < 4; ++r) {
            va[r]  = *reinterpret_cast<const uint2*>(hGt + (r * 4 + q) * 64 + 4 * c);
            vc2[r] = *reinterpret_cast<const uint2*>(hGt + 1024 + (r * 4 + q) * 64 + 4 * c);
        }
        #pragma unroll
        for (int r = 0; r < 4; ++r) {
            *reinterpret_cast<uint2*>(&ha[(q * 4 + r) * 72 + 4 * c]) = va[r];
            *reinterpret_cast<uint2*>(&hc[(q * 4 + r) * 72 + 4 * c]) = vc2[r];
        }
        // layer-2 A-frags (wave-local transpose read)
        bf8 xa[2], xc[2];
        #pragma unroll
        for (int kb = 0; kb < 2; ++kb) {
            xa[kb] = *reinterpret_cast<const bf8*>(&ha[c * 72 + kb * 32 + q * 8]);
            xc[kb] = *reinterpret_cast<const bf8*>(&hc[c * 72 + kb * 32 + q * 8]);
        }

        // ---- layer 2 (bias via acc init) ----
        f32x4 aa[4], ac[4];
        #pragma unroll
        for (int nt = 0; nt < 4; ++nt) {
            aa[nt] = f32x4{b2v[nt], b2v[nt], b2v[nt], b2v[nt]};
            ac[nt] = f32x4{bc2v[nt], bc2v[nt], bc2v[nt], bc2v[nt]};
        }
        #pragma unroll
        for (int kb = 0; kb < 2; ++kb) {
            #pragma unroll
            for (int nt = 0; nt < 4; ++nt) {
                aa[nt] = __builtin_amdgcn_mfma_f32_16x16x32_bf16(xa[kb], fW2L [(kb * 4 + nt) * 64 + l], aa[nt], 0, 0, 0);
                ac[nt] = __builtin_amdgcn_mfma_f32_16x16x32_bf16(xc[kb], fWc2L[(kb * 4 + nt) * 64 + l], ac[nt], 0, 0, 0);
            }
        }
        #pragma unroll
        for (int r = 0; r < 4; ++r) {
            uint2 pa, pc;
            pa.x = pk2(fast_tanh(aa[0][r]), fast_tanh(aa[1][r]));
            pa.y = pk2(fast_tanh(aa[2][r]), fast_tanh(aa[3][r]));
            pc.x = pk2(fast_tanh(ac[0][r]), fast_tanh(ac[1][r]));
            pc.y = pk2(fast_tanh(ac[2][r]), fast_tanh(ac[3][r]));
            *reinterpret_cast<uint2*>(&ha[(q * 4 + r) * 72 + 4 * c]) = pa;
            *reinterpret_cast<uint2*>(&hc[(q * 4 + r) * 72 + 4 * c]) = pc;
        }

        // ---- head: feat[16x64] @ [64x16] (cols 0-14 logits, col 15 value) ----
        {
            f32x4 lg = f32x4{bhv, bhv, bhv, bhv};
            f32x4 vv = f32x4{bhv, bhv, bhv, bhv};
            #pragma unroll
            for (int kb = 0; kb < 2; ++kb) {
                bf8 bw = fWhL[kb * 64 + l];
                bf8 fa = *reinterpret_cast<const bf8*>(&ha[c * 72 + kb * 32 + q * 8]);
                bf8 fc = *reinterpret_cast<const bf8*>(&hc[c * 72 + kb * 32 + q * 8]);
                lg = __builtin_amdgcn_mfma_f32_16x16x32_bf16(fa, bw, lg, 0, 0, 0);
                vv = __builtin_amdgcn_mfma_f32_16x16x32_bf16(fc, bw, vv, 0, 0, 0);
            }
            #pragma unroll
            for (int r = 0; r < 4; ++r)
                lw[(q * 4 + r) * 18 + c] = f2bs(lg[r]);
            if (c == 15) {
                #pragma unroll
                for (int r = 0; r < 4; ++r)
                    vb[q * 4 + r] = vv[r];
            }
        }

        // ---- epilogue: lanes 0-15 (wave-local LDS, in-order DS pipe) ----
        if (l < 16) {
            float lg[5];
            #pragma unroll
            for (int a = 0; a < 5; ++a)
                lg[a] = bs2f(lw[c * 18 + evc * 5 + a]);
            float mx = lg[0];
            #pragma unroll
            for (int a = 1; a < 5; ++a) mx = fmaxf(mx, lg[a]);
            float se = 0.f;
            #pragma unroll
            for (int a = 0; a < 5; ++a) se += __expf(lg[a] - mx);
            float lse = __logf(se) + mx;
            float lsel = lg[0];
            #pragma unroll
            for (int a = 1; a < 5; ++a) lsel = (act == a) ? lg[a] : lsel;
            float ent = 0.f;
            #pragma unroll
            for (int a = 0; a < 5; ++a) { float lp = lg[a] - lse; ent -= __expf(lp) * lp; }

            out[gm]          = (float)act;
            out[Bt + gm]     = lsel - lse;
            out[2 * Bt + gm] = ent;
            out[3 * Bt + gm] = vb[c];
        }
    }
}

extern "C" void kernel_launch(void* const* d_in, const int* in_sizes, int n_in,
                              void* d_out, int out_size, void* d_ws, size_t ws_size,
                              hipStream_t stream) {
    const float* x   = (const float*)d_in[0];
    const int*   act = (const int*)  d_in[1];
    const float* W1  = (const float*)d_in[2];
    const float* b1  = (const float*)d_in[3];
    const float* W2  = (const float*)d_in[4];
    const float* b2  = (const float*)d_in[5];
    const float* Wh  = (const float*)d_in[6];
    const float* bh  = (const float*)d_in[7];
    const float* Wc1 = (const float*)d_in[8];
    const float* bc1 = (const float*)d_in[9];
    const float* Wc2 = (const float*)d_in[10];
    const float* bc2 = (const float*)d_in[11];
    const float* Wc3 = (const float*)d_in[12];
    const float* bc3 = (const float*)d_in[13];
    float* out = (float*)d_out;
    short* ws  = (short*)d_ws;
    short* hG  = ws + HG_S;
    unsigned char* evG = (unsigned char*)d_ws + EVG_B;

    hipLaunchKernelGGL(prep, dim3(32), dim3(256), 0, stream,
                       W1, b1, W2, Wh, Wc1, bc1, Wc2, Wc3, ws);
    hipLaunchKernelGGL(trunk1, dim3(1024), dim3(512), 0, stream,
                       x, ws, hG, evG);
    hipLaunchKernelGGL(head2, dim3(512), dim3(512), 0, stream,
                       act, b2, bc2, bh, bc3, ws, hG, evG, out);
}

// Round 6
// 185.039 us; speedup vs baseline: 1.6835x; 1.0650x over previous
//
#include <hip/hip_runtime.h>
#include <hip/hip_bf16.h>

constexpr int Bt    = 131072;
constexpr int OBS   = 194;

// ---- d_ws layout ----
// bytes [0, 57344)     : W1B | WC1B   (layer-1 B-frags, bf16) -> staged to LDS
// bytes [57344, 92160) : W2B | WC2B | WHB (layer-2 + head B-frags) -> read from L2
constexpr int W1B_S  = 0;
constexpr int WC1B_S = 14336;
constexpr int W2B_S  = 28672;
constexpr int WC2B_S = 36864;
constexpr int WHB_S  = 45056;

typedef short bf8   __attribute__((ext_vector_type(8)));
typedef float f32x4 __attribute__((ext_vector_type(4)));
typedef unsigned int u32;

__device__ __forceinline__ short f2bs(float f) {
    union { __hip_bfloat16 h; short s; } u;
    u.h = __float2bfloat16(f);
    return u.s;
}
__device__ __forceinline__ float bs2f(short s) {
    union { short s; __hip_bfloat16 h; } u;
    u.s = s;
    return __bfloat162float(u.h);
}
__device__ __forceinline__ u32 pk2(float a, float b) {
    union { __hip_bfloat162 h; u32 u; } r;
    r.h = __float22bfloat162_rn(float2{a, b});
    return r.u;
}
__device__ __forceinline__ float fast_tanh(float v) {
    v = fminf(fmaxf(v, -15.f), 15.f);
    float e = __expf(2.f * v);
    return (e - 1.f) * __builtin_amdgcn_rcpf(e + 1.f);
}
// g: per-lane global address. s: WAVE-UNIFORM LDS base — HW writes lane i at s + i*16.
__device__ __forceinline__ void dma16(const void* g, void* s) {
    __builtin_amdgcn_global_load_lds(
        (const __attribute__((address_space(1))) u32*)g,
        (__attribute__((address_space(3))) u32*)s, 16, 0, 0);
}

// ---------------- prep: weights -> B-fragment layout in d_ws (unchanged) ----------------
__global__ void __launch_bounds__(256) prep(
    const float* __restrict__ W1, const float* __restrict__ b1,
    const float* __restrict__ W2, const float* __restrict__ Wh,
    const float* __restrict__ Wc1, const float* __restrict__ bc1,
    const float* __restrict__ Wc2, const float* __restrict__ Wc3,
    short* __restrict__ ws)
{
    const int gid = blockIdx.x * 256 + threadIdx.x;
    const int gsz = gridDim.x * 256;

    for (int i = gid; i < 14336; i += gsz) {
        int j = i & 7, l = (i >> 3) & 63, nt = (i >> 9) & 3, kb = i >> 11;
        int k = kb * 32 + ((l >> 4) << 3) + j;
        int n = nt * 16 + (l & 15);
        short v1 = 0, v2 = 0;
        if (k < OBS) {
            v1 = f2bs(W1[k * 64 + n]);
            v2 = f2bs(Wc1[k * 64 + n]);
        } else if (k == OBS) {              // bias row (A supplies 1.0)
            v1 = f2bs(b1[n]);
            v2 = f2bs(bc1[n]);
        }
        ws[W1B_S + i]  = v1;
        ws[WC1B_S + i] = v2;
    }
    for (int i = gid; i < 8192; i += gsz) {
        int j = i & 7, l = (i >> 3) & 63, nt = (i >> 9) & 3, kb = i >> 11;
        int s = kb * 32 + ((l >> 4) << 3) + j;
        int kp = (s & 3) * 16 + (s >> 2);   // gamma(s)
        int n = nt * 16 + (l & 15);
        ws[W2B_S + i]  = f2bs(W2[kp * 64 + n]);
        ws[WC2B_S + i] = f2bs(Wc2[kp * 64 + n]);
    }
    for (int i = gid; i < 1024; i += gsz) {
        int j = i & 7, l = (i >> 3) & 63, kb = i >> 9;
        int s = kb * 32 + ((l >> 4) << 3) + j;
        int kp = (s & 3) * 16 + (s >> 2);
        int cc = l & 15;
        float v;
        if (cc == 15) v = Wc3[kp];
        else { int e = cc / 5, a = cc - 5 * e; v = Wh[(e * 64 + kp) * 5 + a]; }
        ws[WHB_S + i] = f2bs(v);
    }
}

// ---------------- fused: trunk + head + epilogue, one wave per 16-row tile ----------------
// LDS: layer-1 weights (56 KB, block-shared) + per-wave 2304-B bounce buffer reused
// sequentially (h_a -> h_c -> feat_a -> feat_c -> logits|value). 75776 B -> 2 blocks/CU.
// Layer-2/head B-frags are read from global (35 KB, L2-hot, 1-KB coalesced per instr).
// ev/act/epilogue all stay in the lane that owns the row: no inter-wave traffic at all.
constexpr int FB_LDS = 57344 + 8 * 2304;   // 75776

__global__ void __launch_bounds__(512, 2) fused_ac(
    const float* __restrict__ x, const int* __restrict__ act_in,
    const float* __restrict__ b2, const float* __restrict__ bc2,
    const float* __restrict__ bh, const float* __restrict__ bc3,
    const short* __restrict__ ws,
    float* __restrict__ out)
{
    __shared__ __align__(16) char smem[FB_LDS];
    const int t = threadIdx.x;
    const int l = t & 63, q = (t >> 4) & 3, c = t & 15;
    const int wu = __builtin_amdgcn_readfirstlane(t >> 6);   // wave id, SGPR

    // layer-1 weights -> LDS: 56 x 1024-B chunks, 7 per wave, uniform dest
    #pragma unroll
    for (int i = 0; i < 7; ++i) {
        int ch = wu * 7 + i;
        dma16((const char*)ws + ch * 1024 + l * 16, smem + ch * 1024);
    }

    const bf8* fW1L  = reinterpret_cast<const bf8*>(smem);
    const bf8* fWc1L = reinterpret_cast<const bf8*>(smem + 28672);
    short* bb = reinterpret_cast<short*>(smem + 57344 + wu * 2304);  // per-wave bounce

    const int tt = blockIdx.x * 8 + wu;              // 1024 blocks x 8 waves = 8192 tiles
    const float* xr = x + (size_t)tt * 16 * OBS + (size_t)c * OBS;

    // ---- x load + pack in one step: lane (q,c) holds A[row=c][k = kb*32+q*8 .. +8) ----
    union AF { u32 u[4]; bf8 v; } af[7];
    float4 f40;                                      // row c floats 0-3 (valid for q==0)
    #pragma unroll
    for (int kb = 0; kb < 6; ++kb) {
        float4 a = *reinterpret_cast<const float4*>(xr + kb * 32 + q * 8);
        float4 b = *reinterpret_cast<const float4*>(xr + kb * 32 + q * 8 + 4);
        if (kb == 0) f40 = a;
        af[kb].u[0] = pk2(a.x, a.y);
        af[kb].u[1] = pk2(a.z, a.w);
        af[kb].u[2] = pk2(b.x, b.y);
        af[kb].u[3] = pk2(b.z, b.w);
    }
    af[6].u[0] = 0; af[6].u[1] = 0; af[6].u[2] = 0; af[6].u[3] = 0;
    if (q == 0) {                       // k=192,193 data; k=194 -> 1.0 (bias row)
        float2 v = *reinterpret_cast<const float2*>(xr + 192);
        af[6].u[0] = pk2(v.x, v.y);
        af[6].u[1] = pk2(1.0f, 0.0f);
    }

    // ---- ev = argmax(x[0..2]) + action, kept IN-LANE (l<16 lanes own row c==l) ----
    int act = 0, evc = 0;
    if (l < 16) {
        act = act_in[tt * 16 + l];
        float b = f40.x;
        if (f40.y > b) { b = f40.y; evc = 1; }
        if (f40.z > b) evc = 2;
    }

    // ---- per-lane biases ----
    float b2v[4], bc2v[4];
    #pragma unroll
    for (int nt = 0; nt < 4; ++nt) {
        b2v[nt]  = b2[nt * 16 + c];
        bc2v[nt] = bc2[nt * 16 + c];
    }
    float bhv = (c < 15) ? bh[c] : bc3[0];

    __syncthreads();   // weights resident

    // ---- layer 1: actor + critic (bias folded via k=194 row) ----
    f32x4 aa[4], ac[4];
    #pragma unroll
    for (int nt = 0; nt < 4; ++nt) {
        aa[nt] = f32x4{0.f, 0.f, 0.f, 0.f};
        ac[nt] = f32x4{0.f, 0.f, 0.f, 0.f};
    }
    #pragma unroll
    for (int kb = 0; kb < 7; ++kb) {
        bf8 a = af[kb].v;
        #pragma unroll
        for (int nt = 0; nt < 4; ++nt) {
            aa[nt] = __builtin_amdgcn_mfma_f32_16x16x32_bf16(a, fW1L [(kb * 4 + nt) * 64 + l], aa[nt], 0, 0, 0);
            ac[nt] = __builtin_amdgcn_mfma_f32_16x16x32_bf16(a, fWc1L[(kb * 4 + nt) * 64 + l], ac[nt], 0, 0, 0);
        }
    }

    // ---- bounce helper: write packed tanh(C), read back two A-frags (wave-local,
    //      in-order DS pipe; same buffer reused sequentially) ----
    auto bounce = [&](f32x4* cc4, bf8* fr) {
        #pragma unroll
        for (int r = 0; r < 4; ++r) {
            uint2 p;
            p.x = pk2(fast_tanh(cc4[0][r]), fast_tanh(cc4[1][r]));
            p.y = pk2(fast_tanh(cc4[2][r]), fast_tanh(cc4[3][r]));
            *reinterpret_cast<uint2*>(&bb[(q * 4 + r) * 72 + 4 * c]) = p;
        }
        #pragma unroll
        for (int kb = 0; kb < 2; ++kb)
            fr[kb] = *reinterpret_cast<const bf8*>(&bb[c * 72 + kb * 32 + q * 8]);
    };

    // ---- transpose h through the bounce buffer (actor, then critic) ----
    bf8 xa[2], xc[2];
    bounce(aa, xa);
    bounce(ac, xc);

    // ---- layer 2 (bias via acc init); B-frags streamed from global (L2-hot) ----
    const bf8* fW2G  = reinterpret_cast<const bf8*>((const char*)ws + 57344);
    const bf8* fWc2G = reinterpret_cast<const bf8*>((const char*)ws + 73728);
    const bf8* fWhG  = reinterpret_cast<const bf8*>((const char*)ws + 90112);
    #pragma unroll
    for (int nt = 0; nt < 4; ++nt) {
        aa[nt] = f32x4{b2v[nt], b2v[nt], b2v[nt], b2v[nt]};
        ac[nt] = f32x4{bc2v[nt], bc2v[nt], bc2v[nt], bc2v[nt]};
    }
    #pragma unroll
    for (int kb = 0; kb < 2; ++kb) {
        #pragma unroll
        for (int nt = 0; nt < 4; ++nt) {
            aa[nt] = __builtin_amdgcn_mfma_f32_16x16x32_bf16(xa[kb], fW2G [(kb * 4 + nt) * 64 + l], aa[nt], 0, 0, 0);
            ac[nt] = __builtin_amdgcn_mfma_f32_16x16x32_bf16(xc[kb], fWc2G[(kb * 4 + nt) * 64 + l], ac[nt], 0, 0, 0);
        }
    }

    // ---- transpose feat through the bounce buffer (actor, then critic) ----
    bf8 fa[2], fc[2];
    bounce(aa, fa);
    bounce(ac, fc);

    // ---- head: feat[16x64] @ [64x16] (cols 0-14 logits, col 15 value) ----
    f32x4 lg = f32x4{bhv, bhv, bhv, bhv};
    f32x4 vv = f32x4{bhv, bhv, bhv, bhv};
    #pragma unroll
    for (int kb = 0; kb < 2; ++kb) {
        bf8 bw = fWhG[kb * 64 + l];
        lg = __builtin_amdgcn_mfma_f32_16x16x32_bf16(fa[kb], bw, lg, 0, 0, 0);
        vv = __builtin_amdgcn_mfma_f32_16x16x32_bf16(fc[kb], bw, vv, 0, 0, 0);
    }

    // ---- logits|value -> bounce buffer (lw at 0, vb at shorts 2240..) ----
    short* lw = bb;
    float* vb = reinterpret_cast<float*>(bb + 1120);   // 64 B at tail of 2304-B buffer
    #pragma unroll
    for (int r = 0; r < 4; ++r)
        lw[(q * 4 + r) * 18 + c] = f2bs(lg[r]);
    if (c == 15) {
        #pragma unroll
        for (int r = 0; r < 4; ++r)
            vb[q * 4 + r] = vv[r];
    }

    // ---- epilogue: lanes 0-15 (row c==l), all inputs wave-local ----
    if (l < 16) {
        float lgv[5];
        #pragma unroll
        for (int a = 0; a < 5; ++a)
            lgv[a] = bs2f(lw[c * 18 + evc * 5 + a]);
        float mx = lgv[0];
        #pragma unroll
        for (int a = 1; a < 5; ++a) mx = fmaxf(mx, lgv[a]);
        float se = 0.f;
        #pragma unroll
        for (int a = 0; a < 5; ++a) se += __expf(lgv[a] - mx);
        float lse = __logf(se) + mx;
        float lsel = lgv[0];
        #pragma unroll
        for (int a = 1; a < 5; ++a) lsel = (act == a) ? lgv[a] : lsel;
        float ent = 0.f;
        #pragma unroll
        for (int a = 0; a < 5; ++a) { float lp = lgv[a] - lse; ent -= __expf(lp) * lp; }

        const int gm = tt * 16 + c;
        out[gm]          = (float)act;
        out[Bt + gm]     = lsel - lse;
        out[2 * Bt + gm] = ent;
        out[3 * Bt + gm] = vb[c];
    }
}

extern "C" void kernel_launch(void* const* d_in, const int* in_sizes, int n_in,
                              void* d_out, int out_size, void* d_ws, size_t ws_size,
                              hipStream_t stream) {
    const float* x   = (const float*)d_in[0];
    const int*   act = (const int*)  d_in[1];
    const float* W1  = (const float*)d_in[2];
    const float* b1  = (const float*)d_in[3];
    const float* W2  = (const float*)d_in[4];
    const float* b2  = (const float*)d_in[5];
    const float* Wh  = (const float*)d_in[6];
    const float* bh  = (const float*)d_in[7];
    const float* Wc1 = (const float*)d_in[8];
    const float* bc1 = (const float*)d_in[9];
    const float* Wc2 = (const float*)d_in[10];
    const float* bc2 = (const float*)d_in[11];
    const float* Wc3 = (const float*)d_in[12];
    const float* bc3 = (const float*)d_in[13];
    float* out = (float*)d_out;
    short* ws  = (short*)d_ws;

    hipLaunchKernelGGL(prep, dim3(32), dim3(256), 0, stream,
                       W1, b1, W2, Wh, Wc1, bc1, Wc2, Wc3, ws);
    hipLaunchKernelGGL(fused_ac, dim3(1024), dim3(512), 0, stream,
                       x, act, b2, bc2, bh, bc3, ws, out);
}